// Round 1
// baseline (6940.069 us; speedup 1.0000x reference)
//
#include <hip/hip_runtime.h>
#include <math.h>

#define NN 2048
#define BB 32
#define LL 12
#define HHH 12
#define UU 64
#define CE 66                 // padded channel count (enc: 2+64, dec: 1+64+pad)
#define WID (BB*CE)           // 2112
#define MR (NN*BB)            // 65536
#define SEGW 528              // WID/4
#define CSR_CAP 262144

// ---------- virtual concatenated-input read: cat[r][c], r = n*BB + b ----------
// MODE 1: encoder cat = [x_t(2ch from history), h(64)]
// MODE 2: decoder cat = [xin(1ch), h(64), zero-pad]
template<int MODE>
__device__ __forceinline__ float vcat_r(const float* __restrict__ inp,
                                        const float* __restrict__ h,
                                        int t, int r, int c) {
  if constexpr (MODE == 1) {
    if (c < 2) {
      int n = r >> 5, b = r & 31;
      return inp[((size_t)(b*LL + t)*NN + n)*2 + c];
    }
    return h[(size_t)r*UU + (c - 2)];
  } else {
    if (c == 0) return inp[r];
    if (c < 65) return h[(size_t)r*UU + (c - 1)];
    return 0.0f;
  }
}

__device__ __forceinline__ float sigm(float x) { return 1.0f / (1.0f + __expf(-x)); }

// ---------------- CSR build (deterministic) ----------------
__global__ __launch_bounds__(256) void k_row_count(const float* __restrict__ S, int* __restrict__ cnt) {
  int m = blockIdx.x;
  const float* row = S + (size_t)m * NN;
  int c = 0;
  for (int i = threadIdx.x; i < NN; i += 256) c += (row[i] != 0.0f);
  __shared__ int sm[4];
  for (int off = 32; off; off >>= 1) c += __shfl_down(c, off, 64);
  if ((threadIdx.x & 63) == 0) sm[threadIdx.x >> 6] = c;
  __syncthreads();
  if (threadIdx.x == 0) cnt[m] = sm[0] + sm[1] + sm[2] + sm[3];
}

__global__ __launch_bounds__(256) void k_scan(const int* __restrict__ cnt, int* __restrict__ rp) {
  __shared__ int tot[256];
  int t = threadIdx.x;
  int base = t * 8;
  int v[8]; int s = 0;
  #pragma unroll
  for (int k = 0; k < 8; ++k) { v[k] = cnt[base + k]; s += v[k]; }
  tot[t] = s;
  __syncthreads();
  for (int off = 1; off < 256; off <<= 1) {
    int add = (t >= off) ? tot[t - off] : 0;
    __syncthreads();
    tot[t] += add;
    __syncthreads();
  }
  int run = (t == 0) ? 0 : tot[t - 1];
  #pragma unroll
  for (int k = 0; k < 8; ++k) { rp[base + k] = run; run += v[k]; }
  if (t == 255) rp[NN] = run;
}

__global__ __launch_bounds__(256) void k_fill(const float* __restrict__ S, const int* __restrict__ rp,
                                              int* __restrict__ cols, float* __restrict__ vals) {
  int m = blockIdx.x;
  const float* row = S + (size_t)m * NN;
  __shared__ int wsum[4];
  __shared__ int chunkbase;
  if (threadIdx.x == 0) chunkbase = rp[m];
  __syncthreads();
  int lane = threadIdx.x & 63, w = threadIdx.x >> 6;
  for (int ch = 0; ch < NN / 256; ++ch) {
    int i = ch * 256 + threadIdx.x;
    float val = row[i];
    bool p = (val != 0.0f);
    unsigned long long mask = __ballot(p);
    int rank = __popcll(mask & ((1ull << lane) - 1ull));
    if (lane == 0) wsum[w] = __popcll(mask);
    __syncthreads();
    int off = 0;
    for (int q = 0; q < w; ++q) off += wsum[q];
    if (p) { int k = chunkbase + off + rank; cols[k] = i; vals[k] = val; }
    __syncthreads();
    if (threadIdx.x == 0) chunkbase += wsum[0] + wsum[1] + wsum[2] + wsum[3];
    __syncthreads();
  }
}

// ---------------- weight reorder: W'[kb][c][o] = W[c*3+kb][o], pad c>=Creal ----------------
__global__ __launch_bounds__(256) void k_reorder(const float* __restrict__ Wsrc, float* __restrict__ Wdst,
                                                 int Creal, int NO) {
  int i = blockIdx.x * 256 + threadIdx.x;
  int tot = 3 * CE * NO;
  if (i >= tot) return;
  int o = i % NO; int rc = i / NO; int c = rc % CE; int kb = rc / CE;
  Wdst[i] = (c < Creal) ? Wsrc[(c * 3 + kb) * NO + o] : 0.0f;
}

// ---------------- sparse diffusion: Y[m] = S.row(m) . X  (optionally Y = 2*acc - X0) ----------------
// SRC: 0 plain tensor [N][WID]; 1 enc virtual cat; 2 dec virtual cat. X0M: -1 none, else same coding.
template<int SRC, int X0M>
__global__ __launch_bounds__(256) void k_spmm(
    const int* __restrict__ rp, const int* __restrict__ cols, const float* __restrict__ vals,
    const float* __restrict__ sp, const float* __restrict__ si, const float* __restrict__ sh,
    const float* __restrict__ xp, const float* __restrict__ xi, const float* __restrict__ xh,
    float* __restrict__ Y, int t) {
  int orig = blockIdx.x;
  int swz = (orig & 7) * 1024 + (orig >> 3);   // bijective XCD swizzle (8192 % 8 == 0)
  int seg = swz >> 11;
  int m   = swz & 2047;
  int j0 = rp[m], j1 = rp[m + 1];
  int tid = threadIdx.x;
  float acc0 = 0.f, acc1 = 0.f, acc2 = 0.f;
  int w0 = seg * SEGW + tid, w1 = w0 + 256, w2 = w0 + 512;
  bool a2 = (512 + tid) < SEGW;
  int b0 = w0 / CE, c0_ = w0 % CE;
  int b1 = w1 / CE, c1_ = w1 % CE;
  int b2 = w2 / CE, c2_ = w2 % CE;
  for (int j = j0; j < j1; ++j) {
    int n = cols[j]; float s = vals[j];
    if constexpr (SRC == 0) {
      const float* xr = sp + (size_t)n * WID;
      acc0 = fmaf(s, xr[w0], acc0);
      acc1 = fmaf(s, xr[w1], acc1);
      if (a2) acc2 = fmaf(s, xr[w2], acc2);
    } else {
      acc0 = fmaf(s, vcat_r<SRC>(si, sh, t, n * BB + b0, c0_), acc0);
      acc1 = fmaf(s, vcat_r<SRC>(si, sh, t, n * BB + b1, c1_), acc1);
      if (a2) acc2 = fmaf(s, vcat_r<SRC>(si, sh, t, n * BB + b2, c2_), acc2);
    }
  }
  float* yr = Y + (size_t)m * WID;
  if constexpr (X0M < 0) {
    yr[w0] = acc0; yr[w1] = acc1; if (a2) yr[w2] = acc2;
  } else if constexpr (X0M == 0) {
    const float* x0r = xp + (size_t)m * WID;
    yr[w0] = 2.f * acc0 - x0r[w0];
    yr[w1] = 2.f * acc1 - x0r[w1];
    if (a2) yr[w2] = 2.f * acc2 - x0r[w2];
  } else {
    yr[w0] = 2.f * acc0 - vcat_r<X0M>(xi, xh, t, m * BB + b0, c0_);
    yr[w1] = 2.f * acc1 - vcat_r<X0M>(xi, xh, t, m * BB + b1, c1_);
    if (a2) yr[w2] = 2.f * acc2 - vcat_r<X0M>(xi, xh, t, m * BB + b2, c2_);
  }
}

// ---------------- gate GEMM: ru = sigmoid([cat|T1|T2] @ Wg' + bg); writes z=[x, r*h] and U ----------------
template<int CATM>
__global__ __launch_bounds__(256) void k_gemm_gate(
    const float* __restrict__ inp, const float* __restrict__ h,
    const float* __restrict__ T1, const float* __restrict__ T2,
    const float* __restrict__ Wg, const float* __restrict__ bg,
    float* __restrict__ z, float* __restrict__ Ug, int t) {
  __shared__ __align__(16) float As[66 * 68];
  __shared__ __align__(16) float Wl[66 * 128];
  const int CIN_ = (CATM == 1) ? 2 : 1;
  int r0 = blockIdx.x * 64;
  int tid = threadIdx.x;
  int row0 = (tid >> 4) * 4;
  int c0 = (tid & 15) * 8;
  float acc[4][8];
  #pragma unroll
  for (int i = 0; i < 4; ++i)
    #pragma unroll
    for (int j = 0; j < 8; ++j) acc[i][j] = 0.f;

  for (int kb = 0; kb < 3; ++kb) {
    const float* wsrc = Wg + kb * 66 * 128;
    for (int i = tid; i < 66 * 128; i += 256) Wl[i] = wsrc[i];
    for (int idx = tid; idx < 64 * 66; idx += 256) {
      int rr = idx / 66, cc = idx % 66;
      int r = r0 + rr;
      float v;
      if (kb == 0)      v = vcat_r<CATM>(inp, h, t, r, cc);
      else if (kb == 1) v = T1[(size_t)r * CE + cc];
      else              v = T2[(size_t)r * CE + cc];
      As[cc * 68 + rr] = v;
    }
    __syncthreads();
    for (int kk = 0; kk < 66; ++kk) {
      float4 a4 = *(const float4*)(As + kk * 68 + row0);
      float4 q0 = *(const float4*)(Wl + kk * 128 + c0);
      float4 q1 = *(const float4*)(Wl + kk * 128 + c0 + 4);
      float av[4] = {a4.x, a4.y, a4.z, a4.w};
      float wv[8] = {q0.x, q0.y, q0.z, q0.w, q1.x, q1.y, q1.z, q1.w};
      #pragma unroll
      for (int i = 0; i < 4; ++i)
        #pragma unroll
        for (int j = 0; j < 8; ++j) acc[i][j] = fmaf(av[i], wv[j], acc[i][j]);
    }
    __syncthreads();
  }
  #pragma unroll
  for (int i = 0; i < 4; ++i) {
    int r = r0 + row0 + i;
    #pragma unroll
    for (int j = 0; j < 8; ++j) {
      int col = c0 + j;
      float v = sigm(acc[i][j] + bg[col]);
      if (col < UU) z[(size_t)r * CE + CIN_ + col] = v * h[(size_t)r * UU + col];
      else          Ug[(size_t)r * UU + (col - UU)] = v;
    }
  }
  if ((tid & 15) == 0) {
    #pragma unroll
    for (int i = 0; i < 4; ++i) {
      int r = r0 + row0 + i;
      if (CATM == 1) {
        z[(size_t)r * CE + 0] = vcat_r<1>(inp, h, t, r, 0);
        z[(size_t)r * CE + 1] = vcat_r<1>(inp, h, t, r, 1);
      } else {
        z[(size_t)r * CE + 0] = inp[r];
        z[(size_t)r * CE + 65] = 0.0f;
      }
    }
  }
}

// ---------------- candidate GEMM: c = tanh([z|T1|T2]@Wc'+bc); h_new = u*h + (1-u)*c ----------------
__global__ __launch_bounds__(256) void k_gemm_cand(
    const float* __restrict__ z, const float* __restrict__ T1, const float* __restrict__ T2,
    const float* __restrict__ Wc, const float* __restrict__ bc,
    const float* __restrict__ Ug, const float* __restrict__ hold,
    float* __restrict__ hnew) {
  __shared__ __align__(16) float As[66 * 68];
  __shared__ __align__(16) float Wl[66 * 64];
  int r0 = blockIdx.x * 64;
  int tid = threadIdx.x;
  int row0 = (tid >> 4) * 4;
  int c0 = (tid & 15) * 4;
  float acc[4][4];
  #pragma unroll
  for (int i = 0; i < 4; ++i)
    #pragma unroll
    for (int j = 0; j < 4; ++j) acc[i][j] = 0.f;

  for (int kb = 0; kb < 3; ++kb) {
    const float* wsrc = Wc + kb * 66 * 64;
    for (int i = tid; i < 66 * 64; i += 256) Wl[i] = wsrc[i];
    const float* asrc = (kb == 0) ? z : ((kb == 1) ? T1 : T2);
    for (int idx = tid; idx < 64 * 66; idx += 256) {
      int rr = idx / 66, cc = idx % 66;
      As[cc * 68 + rr] = asrc[(size_t)(r0 + rr) * CE + cc];
    }
    __syncthreads();
    for (int kk = 0; kk < 66; ++kk) {
      float4 a4 = *(const float4*)(As + kk * 68 + row0);
      float4 q0 = *(const float4*)(Wl + kk * 64 + c0);
      float av[4] = {a4.x, a4.y, a4.z, a4.w};
      float wv[4] = {q0.x, q0.y, q0.z, q0.w};
      #pragma unroll
      for (int i = 0; i < 4; ++i)
        #pragma unroll
        for (int j = 0; j < 4; ++j) acc[i][j] = fmaf(av[i], wv[j], acc[i][j]);
    }
    __syncthreads();
  }
  #pragma unroll
  for (int i = 0; i < 4; ++i) {
    int r = r0 + row0 + i;
    #pragma unroll
    for (int j = 0; j < 4; ++j) {
      int col = c0 + j;
      float cf = tanhf(acc[i][j] + bc[col]);
      float u = Ug[(size_t)r * UU + col];
      float ho = hold[(size_t)r * UU + col];
      hnew[(size_t)r * UU + col] = u * ho + (1.0f - u) * cf;
    }
  }
}

// ---------------- output projection: out = h @ Wp + bp; also feeds next decoder input ----------------
__global__ __launch_bounds__(256) void k_out(const float* __restrict__ h,
                                             const float* __restrict__ Wp, const float* __restrict__ bp,
                                             float* __restrict__ out, float* __restrict__ xin, int t) {
  int gtid = blockIdx.x * 256 + threadIdx.x;
  int lane4 = gtid & 3;
  int r = gtid >> 2;
  const float* hr = h + (size_t)r * UU + lane4 * 16;
  const float* wr = Wp + lane4 * 16;
  float s = 0.f;
  #pragma unroll
  for (int k = 0; k < 16; k += 4) {
    float4 v = *(const float4*)(hr + k);
    float4 w = *(const float4*)(wr + k);
    s += v.x * w.x + v.y * w.y + v.z * w.z + v.w * w.w;
  }
  s += __shfl_xor(s, 1, 64);
  s += __shfl_xor(s, 2, 64);
  if (lane4 == 0) {
    float val = s + bp[0];
    int n = r >> 5, b = r & 31;
    out[((size_t)b * HHH + t) * NN + n] = val;
    xin[r] = val;
  }
}

extern "C" void kernel_launch(void* const* d_in, const int* in_sizes, int n_in,
                              void* d_out, int out_size, void* d_ws, size_t ws_size,
                              hipStream_t stream) {
  (void)in_sizes; (void)n_in; (void)out_size; (void)ws_size;
  const float* hist = (const float*)d_in[0];
  const float* support = (const float*)d_in[1];
  const float* eWg = (const float*)d_in[2];
  const float* ebg = (const float*)d_in[3];
  const float* eWc = (const float*)d_in[4];
  const float* ebc = (const float*)d_in[5];
  const float* dWg = (const float*)d_in[6];
  const float* dbg = (const float*)d_in[7];
  const float* dWc = (const float*)d_in[8];
  const float* dbc = (const float*)d_in[9];
  const float* Wp  = (const float*)d_in[10];
  const float* bp  = (const float*)d_in[11];
  float* out = (float*)d_out;

  char* base = (char*)d_ws;
  size_t off = 0;
  auto carve = [&](size_t bytes) -> void* {
    void* p = base + off;
    off += (bytes + 255) & ~(size_t)255;
    return p;
  };
  int*   cnt   = (int*)carve(NN * 4);
  int*   rpB   = (int*)carve((NN + 1) * 4);
  int*   colsB = (int*)carve(CSR_CAP * 4);
  float* valsB = (float*)carve(CSR_CAP * 4);
  float* Wge   = (float*)carve(3 * CE * 128 * 4);
  float* Wce   = (float*)carve(3 * CE * 64 * 4);
  float* Wgd   = (float*)carve(3 * CE * 128 * 4);
  float* Wcd   = (float*)carve(3 * CE * 64 * 4);
  float* T1    = (float*)carve((size_t)NN * WID * 4);
  float* T2    = (float*)carve((size_t)NN * WID * 4);
  float* zB    = (float*)carve((size_t)MR * CE * 4);
  float* Ug    = (float*)carve((size_t)MR * UU * 4);
  float* ha    = (float*)carve((size_t)MR * UU * 4);
  float* hb    = (float*)carve((size_t)MR * UU * 4);
  float* xio   = (float*)carve((size_t)MR * 4);

  hipMemsetAsync(ha, 0, (size_t)MR * UU * 4, stream);
  hipMemsetAsync(xio, 0, (size_t)MR * 4, stream);

  k_row_count<<<NN, 256, 0, stream>>>(support, cnt);
  k_scan<<<1, 256, 0, stream>>>(cnt, rpB);
  k_fill<<<NN, 256, 0, stream>>>(support, rpB, colsB, valsB);
  k_reorder<<<(3 * CE * 128 + 255) / 256, 256, 0, stream>>>(eWg, Wge, 66, 128);
  k_reorder<<<(3 * CE * 64 + 255) / 256, 256, 0, stream>>>(eWc, Wce, 66, 64);
  k_reorder<<<(3 * CE * 128 + 255) / 256, 256, 0, stream>>>(dWg, Wgd, 65, 128);
  k_reorder<<<(3 * CE * 64 + 255) / 256, 256, 0, stream>>>(dWc, Wcd, 65, 64);

  float* hc = ha; float* hn = hb;
  for (int t = 0; t < LL; ++t) {
    k_spmm<1, -1><<<8192, 256, 0, stream>>>(rpB, colsB, valsB, nullptr, hist, hc,
                                            nullptr, nullptr, nullptr, T1, t);
    k_spmm<0, 1><<<8192, 256, 0, stream>>>(rpB, colsB, valsB, T1, nullptr, nullptr,
                                           nullptr, hist, hc, T2, t);
    k_gemm_gate<1><<<MR / 64, 256, 0, stream>>>(hist, hc, T1, T2, Wge, ebg, zB, Ug, t);
    k_spmm<0, -1><<<8192, 256, 0, stream>>>(rpB, colsB, valsB, zB, nullptr, nullptr,
                                            nullptr, nullptr, nullptr, T1, t);
    k_spmm<0, 0><<<8192, 256, 0, stream>>>(rpB, colsB, valsB, T1, nullptr, nullptr,
                                           zB, nullptr, nullptr, T2, t);
    k_gemm_cand<<<MR / 64, 256, 0, stream>>>(zB, T1, T2, Wce, ebc, Ug, hc, hn);
    float* tmp = hc; hc = hn; hn = tmp;
  }
  for (int t = 0; t < HHH; ++t) {
    k_spmm<2, -1><<<8192, 256, 0, stream>>>(rpB, colsB, valsB, nullptr, xio, hc,
                                            nullptr, nullptr, nullptr, T1, t);
    k_spmm<0, 2><<<8192, 256, 0, stream>>>(rpB, colsB, valsB, T1, nullptr, nullptr,
                                           nullptr, xio, hc, T2, t);
    k_gemm_gate<2><<<MR / 64, 256, 0, stream>>>(xio, hc, T1, T2, Wgd, dbg, zB, Ug, t);
    k_spmm<0, -1><<<8192, 256, 0, stream>>>(rpB, colsB, valsB, zB, nullptr, nullptr,
                                            nullptr, nullptr, nullptr, T1, t);
    k_spmm<0, 0><<<8192, 256, 0, stream>>>(rpB, colsB, valsB, T1, nullptr, nullptr,
                                           zB, nullptr, nullptr, T2, t);
    k_gemm_cand<<<MR / 64, 256, 0, stream>>>(zB, T1, T2, Wcd, dbc, Ug, hc, hn);
    k_out<<<MR / 64, 256, 0, stream>>>(hn, Wp, bp, out, xio, t);
    float* tmp = hc; hc = hn; hn = tmp;
  }
}

// Round 2
// 6041.114 us; speedup vs baseline: 1.1488x; 1.1488x over previous
//
#include <hip/hip_runtime.h>
#include <math.h>

#define NN 2048
#define BB 32
#define LL 12
#define HHH 12
#define UU 64
#define CE 66                 // channel count (enc: 2+64, dec: 1+64+pad)
#define WID (BB*CE)           // 2112
#define MR (NN*BB)            // 65536
#define SEGW 528              // WID/4
#define CSR_CAP 262144

// ---------- virtual concatenated-input read: cat[r][c], r = n*BB + b ----------
template<int MODE>
__device__ __forceinline__ float vcat_r(const float* __restrict__ inp,
                                        const float* __restrict__ h,
                                        int t, int r, int c) {
  if constexpr (MODE == 1) {
    if (c < 2) {
      int n = r >> 5, b = r & 31;
      return inp[((size_t)(b*LL + t)*NN + n)*2 + c];
    }
    return h[(size_t)r*UU + (c - 2)];
  } else {
    if (c == 0) return inp[r];
    if (c < 65) return h[(size_t)r*UU + (c - 1)];
    return 0.0f;
  }
}

__device__ __forceinline__ float sigm(float x) { return 1.0f / (1.0f + __expf(-x)); }

// ---------------- CSR build (deterministic) ----------------
__global__ __launch_bounds__(256) void k_row_count(const float* __restrict__ S, int* __restrict__ cnt) {
  int m = blockIdx.x;
  const float* row = S + (size_t)m * NN;
  int c = 0;
  for (int i = threadIdx.x; i < NN; i += 256) c += (row[i] != 0.0f);
  __shared__ int sm[4];
  for (int off = 32; off; off >>= 1) c += __shfl_down(c, off, 64);
  if ((threadIdx.x & 63) == 0) sm[threadIdx.x >> 6] = c;
  __syncthreads();
  if (threadIdx.x == 0) cnt[m] = sm[0] + sm[1] + sm[2] + sm[3];
}

__global__ __launch_bounds__(256) void k_scan(const int* __restrict__ cnt, int* __restrict__ rp) {
  __shared__ int tot[256];
  int t = threadIdx.x;
  int base = t * 8;
  int v[8]; int s = 0;
  #pragma unroll
  for (int k = 0; k < 8; ++k) { v[k] = cnt[base + k]; s += v[k]; }
  tot[t] = s;
  __syncthreads();
  for (int off = 1; off < 256; off <<= 1) {
    int add = (t >= off) ? tot[t - off] : 0;
    __syncthreads();
    tot[t] += add;
    __syncthreads();
  }
  int run = (t == 0) ? 0 : tot[t - 1];
  #pragma unroll
  for (int k = 0; k < 8; ++k) { rp[base + k] = run; run += v[k]; }
  if (t == 255) rp[NN] = run;
}

__global__ __launch_bounds__(256) void k_fill(const float* __restrict__ S, const int* __restrict__ rp,
                                              int* __restrict__ cols, float* __restrict__ vals) {
  int m = blockIdx.x;
  const float* row = S + (size_t)m * NN;
  __shared__ int wsum[4];
  __shared__ int chunkbase;
  if (threadIdx.x == 0) chunkbase = rp[m];
  __syncthreads();
  int lane = threadIdx.x & 63, w = threadIdx.x >> 6;
  for (int ch = 0; ch < NN / 256; ++ch) {
    int i = ch * 256 + threadIdx.x;
    float val = row[i];
    bool p = (val != 0.0f);
    unsigned long long mask = __ballot(p);
    int rank = __popcll(mask & ((1ull << lane) - 1ull));
    if (lane == 0) wsum[w] = __popcll(mask);
    __syncthreads();
    int off = 0;
    for (int q = 0; q < w; ++q) off += wsum[q];
    if (p) { int k = chunkbase + off + rank; cols[k] = i; vals[k] = val; }
    __syncthreads();
    if (threadIdx.x == 0) chunkbase += wsum[0] + wsum[1] + wsum[2] + wsum[3];
    __syncthreads();
  }
}

// ---------------- weight reorder: W'[kb][c][o] = W[c*3+kb][o], pad c>=Creal ----------------
__global__ __launch_bounds__(256) void k_reorder(const float* __restrict__ Wsrc, float* __restrict__ Wdst,
                                                 int Creal, int NO) {
  int i = blockIdx.x * 256 + threadIdx.x;
  int tot = 3 * CE * NO;
  if (i >= tot) return;
  int o = i % NO; int rc = i / NO; int c = rc % CE; int kb = rc / CE;
  Wdst[i] = (c < Creal) ? Wsrc[(c * 3 + kb) * NO + o] : 0.0f;
}

// ---------------- sparse diffusion hop: Y[m] = S.row(m) . X  (opt Y = 2*acc - X0) ----------------
template<int SRC, int X0M>
__global__ __launch_bounds__(256) void k_spmm(
    const int* __restrict__ rp, const int* __restrict__ cols, const float* __restrict__ vals,
    const float* __restrict__ sp, const float* __restrict__ si, const float* __restrict__ sh,
    const float* __restrict__ xp, const float* __restrict__ xi, const float* __restrict__ xh,
    float* __restrict__ Y, int t) {
  __shared__ int   scol[64];
  __shared__ float sval[64];
  int orig = blockIdx.x;
  int swz = (orig & 7) * 1024 + (orig >> 3);   // bijective XCD swizzle (8192 % 8 == 0)
  int seg = swz >> 11;
  int m   = swz & 2047;
  int j0 = rp[m], j1 = rp[m + 1];
  int tid = threadIdx.x;
  float acc0 = 0.f, acc1 = 0.f, acc2 = 0.f;
  int w0 = seg * SEGW + tid, w1 = w0 + 256, w2 = w0 + 512;
  bool a2 = tid < (SEGW - 512);
  int b0 = w0 / CE, c0_ = w0 % CE;
  int b1 = w1 / CE, c1_ = w1 % CE;
  int b2 = w2 / CE, c2_ = w2 % CE;

  auto XV = [&](int n, int w, int b, int c) -> float {
    if constexpr (SRC == 0) return sp[(size_t)n * WID + w];
    else return vcat_r<SRC>(si, sh, t, n * BB + b, c);
  };

  for (int base = j0; base < j1; base += 64) {
    int cnt = min(64, j1 - base);
    if (tid < cnt) { scol[tid] = cols[base + tid]; sval[tid] = vals[base + tid]; }
    __syncthreads();
    int jj = 0;
    for (; jj + 4 <= cnt; jj += 4) {
      int   n0 = scol[jj], n1 = scol[jj+1], n2 = scol[jj+2], n3 = scol[jj+3];
      float s0 = sval[jj], s1 = sval[jj+1], s2 = sval[jj+2], s3 = sval[jj+3];
      float v00 = XV(n0, w0, b0, c0_), v10 = XV(n1, w0, b0, c0_);
      float v20 = XV(n2, w0, b0, c0_), v30 = XV(n3, w0, b0, c0_);
      float v01 = XV(n0, w1, b1, c1_), v11 = XV(n1, w1, b1, c1_);
      float v21 = XV(n2, w1, b1, c1_), v31 = XV(n3, w1, b1, c1_);
      float v02 = 0.f, v12 = 0.f, v22 = 0.f, v32 = 0.f;
      if (a2) {
        v02 = XV(n0, w2, b2, c2_); v12 = XV(n1, w2, b2, c2_);
        v22 = XV(n2, w2, b2, c2_); v32 = XV(n3, w2, b2, c2_);
      }
      acc0 = fmaf(s0, v00, acc0); acc0 = fmaf(s1, v10, acc0);
      acc0 = fmaf(s2, v20, acc0); acc0 = fmaf(s3, v30, acc0);
      acc1 = fmaf(s0, v01, acc1); acc1 = fmaf(s1, v11, acc1);
      acc1 = fmaf(s2, v21, acc1); acc1 = fmaf(s3, v31, acc1);
      acc2 = fmaf(s0, v02, acc2); acc2 = fmaf(s1, v12, acc2);
      acc2 = fmaf(s2, v22, acc2); acc2 = fmaf(s3, v32, acc2);
    }
    for (; jj < cnt; ++jj) {
      int n = scol[jj]; float s = sval[jj];
      acc0 = fmaf(s, XV(n, w0, b0, c0_), acc0);
      acc1 = fmaf(s, XV(n, w1, b1, c1_), acc1);
      if (a2) acc2 = fmaf(s, XV(n, w2, b2, c2_), acc2);
    }
    __syncthreads();
  }

  float* yr = Y + (size_t)m * WID;
  if constexpr (X0M < 0) {
    yr[w0] = acc0; yr[w1] = acc1; if (a2) yr[w2] = acc2;
  } else if constexpr (X0M == 0) {
    const float* x0r = xp + (size_t)m * WID;
    yr[w0] = 2.f * acc0 - x0r[w0];
    yr[w1] = 2.f * acc1 - x0r[w1];
    if (a2) yr[w2] = 2.f * acc2 - x0r[w2];
  } else {
    yr[w0] = 2.f * acc0 - vcat_r<X0M>(xi, xh, t, m * BB + b0, c0_);
    yr[w1] = 2.f * acc1 - vcat_r<X0M>(xi, xh, t, m * BB + b1, c1_);
    if (a2) yr[w2] = 2.f * acc2 - vcat_r<X0M>(xi, xh, t, m * BB + b2, c2_);
  }
}

// ---------------- gate GEMM 128x128: ru = sigmoid([cat|T1|T2] @ Wg' + bg) ----------------
// writes z = [x, r*h] (width 66) and Ug
template<int CATM>
__global__ __launch_bounds__(256, 2) void k_gemm_gate(
    const float* __restrict__ inp, const float* __restrict__ h,
    const float* __restrict__ T1, const float* __restrict__ T2,
    const float* __restrict__ Wg, const float* __restrict__ bg,
    float* __restrict__ z, float* __restrict__ Ug, int t) {
  __shared__ float As[128 * 67];
  __shared__ float Wl[66 * 128];
  const int CIN_ = (CATM == 1) ? 2 : 1;
  int r0 = blockIdx.x * 128;
  int tid = threadIdx.x;
  int rowg = tid >> 4;          // 0..15 -> 8 rows each
  int c0 = (tid & 15) * 8;      // 0..120
  float acc[8][8];
  #pragma unroll
  for (int i = 0; i < 8; ++i)
    #pragma unroll
    for (int j = 0; j < 8; ++j) acc[i][j] = 0.f;
  float bgv[8];
  #pragma unroll
  for (int j = 0; j < 8; ++j) bgv[j] = bg[c0 + j];

  for (int kb = 0; kb < 3; ++kb) {
    const float* ws = Wg + kb * 66 * 128;
    for (int e = tid; e < 66 * 128; e += 256) Wl[e] = ws[e];
    for (int e = tid; e < 128 * 66; e += 256) {
      int rr = e / 66, cc = e - rr * 66;
      int r = r0 + rr;
      float v;
      if (kb == 0)      v = vcat_r<CATM>(inp, h, t, r, cc);
      else if (kb == 1) v = T1[(size_t)r * CE + cc];
      else              v = T2[(size_t)r * CE + cc];
      As[rr * 67 + cc] = v;
    }
    __syncthreads();
    #pragma unroll 2
    for (int kk = 0; kk < 66; ++kk) {
      float a[8], w[8];
      #pragma unroll
      for (int i = 0; i < 8; ++i) a[i] = As[(rowg * 8 + i) * 67 + kk];
      float4 q0 = *(const float4*)(Wl + kk * 128 + c0);
      float4 q1 = *(const float4*)(Wl + kk * 128 + c0 + 4);
      w[0] = q0.x; w[1] = q0.y; w[2] = q0.z; w[3] = q0.w;
      w[4] = q1.x; w[5] = q1.y; w[6] = q1.z; w[7] = q1.w;
      #pragma unroll
      for (int i = 0; i < 8; ++i)
        #pragma unroll
        for (int j = 0; j < 8; ++j) acc[i][j] = fmaf(a[i], w[j], acc[i][j]);
    }
    __syncthreads();
  }

  #pragma unroll
  for (int i = 0; i < 8; ++i) {
    int r = r0 + rowg * 8 + i;
    #pragma unroll
    for (int j = 0; j < 8; ++j) {
      int col = c0 + j;
      float v = sigm(acc[i][j] + bgv[j]);
      if (col < UU) z[(size_t)r * CE + CIN_ + col] = v * h[(size_t)r * UU + col];
      else          Ug[(size_t)r * UU + (col - UU)] = v;
    }
  }
  if ((tid & 15) == 0) {
    #pragma unroll
    for (int i = 0; i < 8; ++i) {
      int r = r0 + rowg * 8 + i;
      if (CATM == 1) {
        z[(size_t)r * CE + 0] = vcat_r<1>(inp, h, t, r, 0);
        z[(size_t)r * CE + 1] = vcat_r<1>(inp, h, t, r, 1);
      } else {
        z[(size_t)r * CE + 0] = inp[r];
        z[(size_t)r * CE + 65] = 0.0f;
      }
    }
  }
}

// ---------------- cand GEMM 128x64: c = tanh([z|T1|T2]@Wc'+bc); h=u*h+(1-u)*c ----------------
// DEC: fused output projection out = h@Wp + bp, also writes xio
template<bool DEC>
__global__ __launch_bounds__(256, 3) void k_gemm_cand(
    const float* __restrict__ z, const float* __restrict__ T1, const float* __restrict__ T2,
    const float* __restrict__ Wc, const float* __restrict__ bc,
    const float* __restrict__ Ug, const float* __restrict__ hold,
    float* __restrict__ hnew,
    const float* __restrict__ Wp, const float* __restrict__ bp,
    float* __restrict__ out, float* __restrict__ xio, int t) {
  __shared__ float As[128 * 67];
  __shared__ float Wl[66 * 64];
  int r0 = blockIdx.x * 128;
  int tid = threadIdx.x;
  int rowg = tid >> 3;          // 0..31 -> 4 rows each
  int c0 = (tid & 7) * 8;       // 0..56
  float acc[4][8];
  #pragma unroll
  for (int i = 0; i < 4; ++i)
    #pragma unroll
    for (int j = 0; j < 8; ++j) acc[i][j] = 0.f;
  float bcv[8], wpv[8];
  #pragma unroll
  for (int j = 0; j < 8; ++j) { bcv[j] = bc[c0 + j]; wpv[j] = DEC ? Wp[c0 + j] : 0.f; }

  for (int kb = 0; kb < 3; ++kb) {
    const float* ws = Wc + kb * 66 * 64;
    for (int e = tid; e < 66 * 64; e += 256) Wl[e] = ws[e];
    const float* asrc = (kb == 0) ? z : ((kb == 1) ? T1 : T2);
    for (int e = tid; e < 128 * 66; e += 256) {
      int rr = e / 66, cc = e - rr * 66;
      As[rr * 67 + cc] = asrc[(size_t)(r0 + rr) * CE + cc];
    }
    __syncthreads();
    #pragma unroll 2
    for (int kk = 0; kk < 66; ++kk) {
      float a[4], w[8];
      #pragma unroll
      for (int i = 0; i < 4; ++i) a[i] = As[(rowg * 4 + i) * 67 + kk];
      float4 q0 = *(const float4*)(Wl + kk * 64 + c0);
      float4 q1 = *(const float4*)(Wl + kk * 64 + c0 + 4);
      w[0] = q0.x; w[1] = q0.y; w[2] = q0.z; w[3] = q0.w;
      w[4] = q1.x; w[5] = q1.y; w[6] = q1.z; w[7] = q1.w;
      #pragma unroll
      for (int i = 0; i < 4; ++i)
        #pragma unroll
        for (int j = 0; j < 8; ++j) acc[i][j] = fmaf(a[i], w[j], acc[i][j]);
    }
    __syncthreads();
  }

  float ps[4];
  #pragma unroll
  for (int i = 0; i < 4; ++i) {
    int r = r0 + rowg * 4 + i;
    float p = 0.f;
    #pragma unroll
    for (int j = 0; j < 8; ++j) {
      int col = c0 + j;
      float cf = tanhf(acc[i][j] + bcv[j]);
      float u  = Ug[(size_t)r * UU + col];
      float ho = hold[(size_t)r * UU + col];
      float hv = u * ho + (1.0f - u) * cf;
      hnew[(size_t)r * UU + col] = hv;
      if (DEC) p = fmaf(hv, wpv[j], p);
    }
    ps[i] = p;
  }
  if (DEC) {
    #pragma unroll
    for (int off = 1; off < 8; off <<= 1)
      #pragma unroll
      for (int i = 0; i < 4; ++i) ps[i] += __shfl_xor(ps[i], off, 64);
    if ((tid & 7) == 0) {
      #pragma unroll
      for (int i = 0; i < 4; ++i) {
        int r = r0 + rowg * 4 + i;
        float val = ps[i] + bp[0];
        int n = r >> 5, b = r & 31;
        out[((size_t)b * HHH + t) * NN + n] = val;
        xio[r] = val;
      }
    }
  }
}

extern "C" void kernel_launch(void* const* d_in, const int* in_sizes, int n_in,
                              void* d_out, int out_size, void* d_ws, size_t ws_size,
                              hipStream_t stream) {
  (void)in_sizes; (void)n_in; (void)out_size; (void)ws_size;
  const float* hist = (const float*)d_in[0];
  const float* support = (const float*)d_in[1];
  const float* eWg = (const float*)d_in[2];
  const float* ebg = (const float*)d_in[3];
  const float* eWc = (const float*)d_in[4];
  const float* ebc = (const float*)d_in[5];
  const float* dWg = (const float*)d_in[6];
  const float* dbg = (const float*)d_in[7];
  const float* dWc = (const float*)d_in[8];
  const float* dbc = (const float*)d_in[9];
  const float* Wp  = (const float*)d_in[10];
  const float* bp  = (const float*)d_in[11];
  float* out = (float*)d_out;

  char* base = (char*)d_ws;
  size_t off = 0;
  auto carve = [&](size_t bytes) -> void* {
    void* p = base + off;
    off += (bytes + 255) & ~(size_t)255;
    return p;
  };
  int*   cnt   = (int*)carve(NN * 4);
  int*   rpB   = (int*)carve((NN + 1) * 4);
  int*   colsB = (int*)carve(CSR_CAP * 4);
  float* valsB = (float*)carve(CSR_CAP * 4);
  float* Wge   = (float*)carve(3 * CE * 128 * 4);
  float* Wce   = (float*)carve(3 * CE * 64 * 4);
  float* Wgd   = (float*)carve(3 * CE * 128 * 4);
  float* Wcd   = (float*)carve(3 * CE * 64 * 4);
  float* T1    = (float*)carve((size_t)NN * WID * 4);
  float* T2    = (float*)carve((size_t)NN * WID * 4);
  float* zB    = (float*)carve((size_t)MR * CE * 4);
  float* Ug    = (float*)carve((size_t)MR * UU * 4);
  float* ha    = (float*)carve((size_t)MR * UU * 4);
  float* hb    = (float*)carve((size_t)MR * UU * 4);
  float* xio   = (float*)carve((size_t)MR * 4);

  hipMemsetAsync(ha, 0, (size_t)MR * UU * 4, stream);
  hipMemsetAsync(xio, 0, (size_t)MR * 4, stream);

  k_row_count<<<NN, 256, 0, stream>>>(support, cnt);
  k_scan<<<1, 256, 0, stream>>>(cnt, rpB);
  k_fill<<<NN, 256, 0, stream>>>(support, rpB, colsB, valsB);
  k_reorder<<<(3 * CE * 128 + 255) / 256, 256, 0, stream>>>(eWg, Wge, 66, 128);
  k_reorder<<<(3 * CE * 64 + 255) / 256, 256, 0, stream>>>(eWc, Wce, 66, 64);
  k_reorder<<<(3 * CE * 128 + 255) / 256, 256, 0, stream>>>(dWg, Wgd, 65, 128);
  k_reorder<<<(3 * CE * 64 + 255) / 256, 256, 0, stream>>>(dWc, Wcd, 65, 64);

  float* hc = ha; float* hn = hb;
  for (int t = 0; t < LL; ++t) {
    k_spmm<1, -1><<<8192, 256, 0, stream>>>(rpB, colsB, valsB, nullptr, hist, hc,
                                            nullptr, nullptr, nullptr, T1, t);
    k_spmm<0, 1><<<8192, 256, 0, stream>>>(rpB, colsB, valsB, T1, nullptr, nullptr,
                                           nullptr, hist, hc, T2, t);
    k_gemm_gate<1><<<MR / 128, 256, 0, stream>>>(hist, hc, T1, T2, Wge, ebg, zB, Ug, t);
    k_spmm<0, -1><<<8192, 256, 0, stream>>>(rpB, colsB, valsB, zB, nullptr, nullptr,
                                            nullptr, nullptr, nullptr, T1, t);
    k_spmm<0, 0><<<8192, 256, 0, stream>>>(rpB, colsB, valsB, T1, nullptr, nullptr,
                                           zB, nullptr, nullptr, T2, t);
    k_gemm_cand<false><<<MR / 128, 256, 0, stream>>>(zB, T1, T2, Wce, ebc, Ug, hc, hn,
                                                     Wp, bp, out, xio, t);
    float* tmp = hc; hc = hn; hn = tmp;
  }
  for (int t = 0; t < HHH; ++t) {
    k_spmm<2, -1><<<8192, 256, 0, stream>>>(rpB, colsB, valsB, nullptr, xio, hc,
                                            nullptr, nullptr, nullptr, T1, t);
    k_spmm<0, 2><<<8192, 256, 0, stream>>>(rpB, colsB, valsB, T1, nullptr, nullptr,
                                           nullptr, xio, hc, T2, t);
    k_gemm_gate<2><<<MR / 128, 256, 0, stream>>>(xio, hc, T1, T2, Wgd, dbg, zB, Ug, t);
    k_spmm<0, -1><<<8192, 256, 0, stream>>>(rpB, colsB, valsB, zB, nullptr, nullptr,
                                            nullptr, nullptr, nullptr, T1, t);
    k_spmm<0, 0><<<8192, 256, 0, stream>>>(rpB, colsB, valsB, T1, nullptr, nullptr,
                                           zB, nullptr, nullptr, T2, t);
    k_gemm_cand<true><<<MR / 128, 256, 0, stream>>>(zB, T1, T2, Wcd, dbc, Ug, hc, hn,
                                                    Wp, bp, out, xio, t);
    float* tmp = hc; hc = hn; hn = tmp;
  }
}

// Round 3
// 4593.499 us; speedup vs baseline: 1.5108x; 1.3151x over previous
//
#include <hip/hip_runtime.h>
#include <math.h>

#define NN 2048
#define BB 32
#define LL 12
#define HHH 12
#define UU 64
#define CE 66                 // row width: [h-part 64 | x-part CIN_ | pad]
#define WID (BB*CE)           // 2112
#define MR (NN*BB)            // 65536
#define SEGW 528              // WID/4
#define CSR_CAP 262144
#define PACK_HALF 28672       // 7ks * 4nf * 2prec * 64lane * 8j halfwords per 64-col half

typedef short bfrag __attribute__((ext_vector_type(8)));
typedef float ffrag __attribute__((ext_vector_type(4)));

// ---------- virtual concatenated-input read (NEW ordering: [h 64 | x CIN_]) ----------
template<int MODE>
__device__ __forceinline__ float vcat_r(const float* __restrict__ inp,
                                        const float* __restrict__ h,
                                        int t, int r, int c) {
  if constexpr (MODE == 1) {
    if (c < 64) return h[(size_t)r*UU + c];
    int q = c - 64;
    int n = r >> 5, b = r & 31;
    return inp[((size_t)(b*LL + t)*NN + n)*2 + q];
  } else {
    if (c < 64) return h[(size_t)r*UU + c];
    if (c == 64) return inp[r];
    return 0.0f;
  }
}

__device__ __forceinline__ float sigm(float x) { return 1.0f / (1.0f + __expf(-x)); }

__device__ __forceinline__ void cvt8(const float* a, bfrag* hi, bfrag* lo) {
  bfrag H, L;
  #pragma unroll
  for (int j = 0; j < 8; ++j) {
    unsigned u = __float_as_uint(a[j]);
    unsigned hb = (u + 0x7FFFu + ((u >> 16) & 1u)) >> 16;
    float rem = a[j] - __uint_as_float(hb << 16);
    unsigned u2 = __float_as_uint(rem);
    unsigned lb = (u2 + 0x7FFFu + ((u2 >> 16) & 1u)) >> 16;
    H[j] = (short)hb; L[j] = (short)lb;
  }
  *hi = H; *lo = L;
}

// ---------------- CSR build (deterministic) ----------------
__global__ __launch_bounds__(256) void k_row_count(const float* __restrict__ S, int* __restrict__ cnt) {
  int m = blockIdx.x;
  const float* row = S + (size_t)m * NN;
  int c = 0;
  for (int i = threadIdx.x; i < NN; i += 256) c += (row[i] != 0.0f);
  __shared__ int sm[4];
  for (int off = 32; off; off >>= 1) c += __shfl_down(c, off, 64);
  if ((threadIdx.x & 63) == 0) sm[threadIdx.x >> 6] = c;
  __syncthreads();
  if (threadIdx.x == 0) cnt[m] = sm[0] + sm[1] + sm[2] + sm[3];
}

__global__ __launch_bounds__(256) void k_scan(const int* __restrict__ cnt, int* __restrict__ rp) {
  __shared__ int tot[256];
  int t = threadIdx.x;
  int base = t * 8;
  int v[8]; int s = 0;
  #pragma unroll
  for (int k = 0; k < 8; ++k) { v[k] = cnt[base + k]; s += v[k]; }
  tot[t] = s;
  __syncthreads();
  for (int off = 1; off < 256; off <<= 1) {
    int add = (t >= off) ? tot[t - off] : 0;
    __syncthreads();
    tot[t] += add;
    __syncthreads();
  }
  int run = (t == 0) ? 0 : tot[t - 1];
  #pragma unroll
  for (int k = 0; k < 8; ++k) { rp[base + k] = run; run += v[k]; }
  if (t == 255) rp[NN] = run;
}

__global__ __launch_bounds__(256) void k_fill(const float* __restrict__ S, const int* __restrict__ rp,
                                              int* __restrict__ cols, float* __restrict__ vals) {
  int m = blockIdx.x;
  const float* row = S + (size_t)m * NN;
  __shared__ int wsum[4];
  __shared__ int chunkbase;
  if (threadIdx.x == 0) chunkbase = rp[m];
  __syncthreads();
  int lane = threadIdx.x & 63, w = threadIdx.x >> 6;
  for (int ch = 0; ch < NN / 256; ++ch) {
    int i = ch * 256 + threadIdx.x;
    float val = row[i];
    bool p = (val != 0.0f);
    unsigned long long mask = __ballot(p);
    int rank = __popcll(mask & ((1ull << lane) - 1ull));
    if (lane == 0) wsum[w] = __popcll(mask);
    __syncthreads();
    int off = 0;
    for (int q = 0; q < w; ++q) off += wsum[q];
    if (p) { int k = chunkbase + off + rank; cols[k] = i; vals[k] = val; }
    __syncthreads();
    if (threadIdx.x == 0) chunkbase += wsum[0] + wsum[1] + wsum[2] + wsum[3];
    __syncthreads();
  }
}

// ---------------- weight pack into MFMA-fragment-linear bf16 hi/lo ----------------
// dst[nh][ks][nf][prec][lane][j]; K-order: ks0-1 h(kb0), ks2-3 T1h(kb1), ks4-5 T2h(kb2),
// ks6: q=grp*8+j -> kb=q/CIN_, c=q%CIN_ (q < 3*CIN_), else 0.
__global__ __launch_bounds__(256) void k_pack(const float* __restrict__ Wsrc, unsigned short* __restrict__ dst,
                                              int CIN_, int NO) {
  int idx = blockIdx.x * 256 + threadIdx.x;
  int nh_count = NO >> 6;
  int tot = nh_count * 7 * 4 * 64 * 8;
  if (idx >= tot) return;
  int j = idx & 7;
  int r1 = idx >> 3;  int lane = r1 & 63;
  int r2 = r1 >> 6;   int nf = r2 & 3;
  int r3 = r2 >> 2;   int ks = r3 % 7; int nh = r3 / 7;
  int grp = lane >> 4, l15 = lane & 15;
  int col = nh*64 + nf*16 + l15;
  float wv = 0.0f;
  if (ks < 6) {
    int kb = ks >> 1;
    int c = CIN_ + (ks & 1)*32 + grp*8 + j;
    wv = Wsrc[((size_t)c*3 + kb)*NO + col];
  } else {
    int q = grp*8 + j;
    if (q < 3*CIN_) { int kb = q / CIN_, c = q % CIN_; wv = Wsrc[((size_t)c*3 + kb)*NO + col]; }
  }
  unsigned u = __float_as_uint(wv);
  unsigned hb = (u + 0x7FFFu + ((u >> 16) & 1u)) >> 16;
  float rem = wv - __uint_as_float(hb << 16);
  unsigned u2 = __float_as_uint(rem);
  unsigned lb = (u2 + 0x7FFFu + ((u2 >> 16) & 1u)) >> 16;
  size_t basehi = ((size_t)nh*PACK_HALF) + ((((size_t)ks*4 + nf)*2 + 0)*64 + lane)*8 + j;
  size_t baselo = ((size_t)nh*PACK_HALF) + ((((size_t)ks*4 + nf)*2 + 1)*64 + lane)*8 + j;
  dst[basehi] = (unsigned short)hb;
  dst[baselo] = (unsigned short)lb;
}

// ---------------- sparse diffusion hop ----------------
template<int SRC, int X0M>
__global__ __launch_bounds__(256) void k_spmm(
    const int* __restrict__ rp, const int* __restrict__ cols, const float* __restrict__ vals,
    const float* __restrict__ sp, const float* __restrict__ si, const float* __restrict__ sh,
    const float* __restrict__ xp, const float* __restrict__ xi, const float* __restrict__ xh,
    float* __restrict__ Y, int t) {
  __shared__ int   scol[64];
  __shared__ float sval[64];
  int orig = blockIdx.x;
  int swz = (orig & 7) * 1024 + (orig >> 3);
  int seg = swz >> 11;
  int m   = swz & 2047;
  int j0 = rp[m], j1 = rp[m + 1];
  int tid = threadIdx.x;
  float acc0 = 0.f, acc1 = 0.f, acc2 = 0.f;
  int w0 = seg * SEGW + tid, w1 = w0 + 256, w2 = w0 + 512;
  bool a2 = tid < (SEGW - 512);
  int b0 = w0 / CE, c0_ = w0 % CE;
  int b1 = w1 / CE, c1_ = w1 % CE;
  int b2 = w2 / CE, c2_ = w2 % CE;

  auto XV = [&](int n, int w, int b, int c) -> float {
    if constexpr (SRC == 0) return sp[(size_t)n * WID + w];
    else return vcat_r<SRC>(si, sh, t, n * BB + b, c);
  };

  for (int base = j0; base < j1; base += 64) {
    int cnt = min(64, j1 - base);
    if (tid < cnt) { scol[tid] = cols[base + tid]; sval[tid] = vals[base + tid]; }
    __syncthreads();
    int jj = 0;
    for (; jj + 4 <= cnt; jj += 4) {
      int   n0 = scol[jj], n1 = scol[jj+1], n2 = scol[jj+2], n3 = scol[jj+3];
      float s0 = sval[jj], s1 = sval[jj+1], s2 = sval[jj+2], s3 = sval[jj+3];
      float v00 = XV(n0, w0, b0, c0_), v10 = XV(n1, w0, b0, c0_);
      float v20 = XV(n2, w0, b0, c0_), v30 = XV(n3, w0, b0, c0_);
      float v01 = XV(n0, w1, b1, c1_), v11 = XV(n1, w1, b1, c1_);
      float v21 = XV(n2, w1, b1, c1_), v31 = XV(n3, w1, b1, c1_);
      float v02 = 0.f, v12 = 0.f, v22 = 0.f, v32 = 0.f;
      if (a2) {
        v02 = XV(n0, w2, b2, c2_); v12 = XV(n1, w2, b2, c2_);
        v22 = XV(n2, w2, b2, c2_); v32 = XV(n3, w2, b2, c2_);
      }
      acc0 = fmaf(s0, v00, acc0); acc0 = fmaf(s1, v10, acc0);
      acc0 = fmaf(s2, v20, acc0); acc0 = fmaf(s3, v30, acc0);
      acc1 = fmaf(s0, v01, acc1); acc1 = fmaf(s1, v11, acc1);
      acc1 = fmaf(s2, v21, acc1); acc1 = fmaf(s3, v31, acc1);
      acc2 = fmaf(s0, v02, acc2); acc2 = fmaf(s1, v12, acc2);
      acc2 = fmaf(s2, v22, acc2); acc2 = fmaf(s3, v32, acc2);
    }
    for (; jj < cnt; ++jj) {
      int n = scol[jj]; float s = sval[jj];
      acc0 = fmaf(s, XV(n, w0, b0, c0_), acc0);
      acc1 = fmaf(s, XV(n, w1, b1, c1_), acc1);
      if (a2) acc2 = fmaf(s, XV(n, w2, b2, c2_), acc2);
    }
    __syncthreads();
  }

  float* yr = Y + (size_t)m * WID;
  if constexpr (X0M < 0) {
    yr[w0] = acc0; yr[w1] = acc1; if (a2) yr[w2] = acc2;
  } else if constexpr (X0M == 0) {
    const float* x0r = xp + (size_t)m * WID;
    yr[w0] = 2.f * acc0 - x0r[w0];
    yr[w1] = 2.f * acc1 - x0r[w1];
    if (a2) yr[w2] = 2.f * acc2 - x0r[w2];
  } else {
    yr[w0] = 2.f * acc0 - vcat_r<X0M>(xi, xh, t, m * BB + b0, c0_);
    yr[w1] = 2.f * acc1 - vcat_r<X0M>(xi, xh, t, m * BB + b1, c1_);
    if (a2) yr[w2] = 2.f * acc2 - vcat_r<X0M>(xi, xh, t, m * BB + b2, c2_);
  }
}

// ---------------- gate GEMM (MFMA bf16x3): ru = sigmoid(A @ Wg + bg) ----------------
// grid = (MR/128)*2; nh=0 -> r-gate, writes z=[r*h | x]; nh=1 -> u-gate, writes Ug
template<int CATM>
__global__ __launch_bounds__(256, 2) void k_gemm_gate(
    const float* __restrict__ inp, const float* __restrict__ h,
    const float* __restrict__ T1, const float* __restrict__ T2,
    const unsigned short* __restrict__ Bpack, const float* __restrict__ bg,
    float* __restrict__ z, float* __restrict__ Ug, int t) {
  __shared__ unsigned short Bl[PACK_HALF];
  const int CIN_ = (CATM == 1) ? 2 : 1;
  int bid = blockIdx.x;
  int nh = bid & 1;
  int r0 = (bid >> 1) * 128;
  int tid = threadIdx.x;
  {
    const float4* src = (const float4*)(Bpack + (size_t)nh * PACK_HALF);
    float4* dst = (float4*)Bl;
    #pragma unroll
    for (int i = 0; i < 14; ++i) dst[tid + 256*i] = src[tid + 256*i];
  }
  __syncthreads();
  int w = tid >> 6, lane = tid & 63, grp = lane >> 4, l15 = lane & 15;
  int row0 = r0 + w*32 + l15;
  int row1 = row0 + 16;
  ffrag acc[2][4];
  #pragma unroll
  for (int m = 0; m < 2; ++m)
    #pragma unroll
    for (int nf = 0; nf < 4; ++nf) acc[m][nf] = (ffrag){0.f, 0.f, 0.f, 0.f};

  #pragma unroll
  for (int ks = 0; ks < 6; ++ks) {
    int ko = (ks & 1)*32 + grp*8;
    const float* p0 = (ks < 2) ? h : ((ks < 4) ? T1 : T2);
    int st = (ks < 2) ? UU : CE;
    const float* a0p = p0 + (size_t)row0*st + ko;
    const float* a1p = p0 + (size_t)row1*st + ko;
    float av0[8], av1[8];
    *(float4*)(av0)   = *(const float4*)a0p; *(float4*)(av0+4) = *(const float4*)(a0p+4);
    *(float4*)(av1)   = *(const float4*)a1p; *(float4*)(av1+4) = *(const float4*)(a1p+4);
    bfrag ah0, al0, ah1, al1;
    cvt8(av0, &ah0, &al0); cvt8(av1, &ah1, &al1);
    #pragma unroll
    for (int nf = 0; nf < 4; ++nf) {
      bfrag bh  = *(const bfrag*)(Bl + ((((size_t)ks*4 + nf)*2 + 0)*64 + lane)*8);
      bfrag blo = *(const bfrag*)(Bl + ((((size_t)ks*4 + nf)*2 + 1)*64 + lane)*8);
      acc[0][nf] = __builtin_amdgcn_mfma_f32_16x16x32_bf16(ah0, bh,  acc[0][nf], 0, 0, 0);
      acc[0][nf] = __builtin_amdgcn_mfma_f32_16x16x32_bf16(ah0, blo, acc[0][nf], 0, 0, 0);
      acc[0][nf] = __builtin_amdgcn_mfma_f32_16x16x32_bf16(al0, bh,  acc[0][nf], 0, 0, 0);
      acc[1][nf] = __builtin_amdgcn_mfma_f32_16x16x32_bf16(ah1, bh,  acc[1][nf], 0, 0, 0);
      acc[1][nf] = __builtin_amdgcn_mfma_f32_16x16x32_bf16(ah1, blo, acc[1][nf], 0, 0, 0);
      acc[1][nf] = __builtin_amdgcn_mfma_f32_16x16x32_bf16(al1, bh,  acc[1][nf], 0, 0, 0);
    }
  }
  { // ks == 6: leftover x-channels (3*CIN_ <= 6), lanes grp==0 only
    float av0[8] = {0,0,0,0,0,0,0,0}, av1[8] = {0,0,0,0,0,0,0,0};
    if (grp == 0) {
      auto gx = [&](int row, float* av) {
        if (CATM == 1) {
          int n = row >> 5, b = row & 31;
          const float* hp = inp + ((size_t)(b*LL + t)*NN + n)*2;
          av[0] = hp[0]; av[1] = hp[1];
          av[2] = T1[(size_t)row*CE + 64]; av[3] = T1[(size_t)row*CE + 65];
          av[4] = T2[(size_t)row*CE + 64]; av[5] = T2[(size_t)row*CE + 65];
        } else {
          av[0] = inp[row];
          av[1] = T1[(size_t)row*CE + 64];
          av[2] = T2[(size_t)row*CE + 64];
        }
      };
      gx(row0, av0); gx(row1, av1);
    }
    bfrag ah0, al0, ah1, al1;
    cvt8(av0, &ah0, &al0); cvt8(av1, &ah1, &al1);
    #pragma unroll
    for (int nf = 0; nf < 4; ++nf) {
      bfrag bh  = *(const bfrag*)(Bl + ((((size_t)6*4 + nf)*2 + 0)*64 + lane)*8);
      bfrag blo = *(const bfrag*)(Bl + ((((size_t)6*4 + nf)*2 + 1)*64 + lane)*8);
      acc[0][nf] = __builtin_amdgcn_mfma_f32_16x16x32_bf16(ah0, bh,  acc[0][nf], 0, 0, 0);
      acc[0][nf] = __builtin_amdgcn_mfma_f32_16x16x32_bf16(ah0, blo, acc[0][nf], 0, 0, 0);
      acc[0][nf] = __builtin_amdgcn_mfma_f32_16x16x32_bf16(al0, bh,  acc[0][nf], 0, 0, 0);
      acc[1][nf] = __builtin_amdgcn_mfma_f32_16x16x32_bf16(ah1, bh,  acc[1][nf], 0, 0, 0);
      acc[1][nf] = __builtin_amdgcn_mfma_f32_16x16x32_bf16(ah1, blo, acc[1][nf], 0, 0, 0);
      acc[1][nf] = __builtin_amdgcn_mfma_f32_16x16x32_bf16(al1, bh,  acc[1][nf], 0, 0, 0);
    }
  }

  float bgv[4];
  #pragma unroll
  for (int nf = 0; nf < 4; ++nf) bgv[nf] = bg[nh*64 + nf*16 + l15];
  #pragma unroll
  for (int m = 0; m < 2; ++m)
    #pragma unroll
    for (int reg = 0; reg < 4; ++reg) {
      int row = r0 + w*32 + m*16 + grp*4 + reg;
      #pragma unroll
      for (int nf = 0; nf < 4; ++nf) {
        float v = sigm(acc[m][nf][reg] + bgv[nf]);
        int col = nf*16 + l15;
        if (nh == 0) z[(size_t)row*CE + col] = v * h[(size_t)row*UU + col];
        else         Ug[(size_t)row*UU + col] = v;
      }
    }
  if (nh == 0 && l15 == 0) {
    #pragma unroll
    for (int m = 0; m < 2; ++m)
      #pragma unroll
      for (int reg = 0; reg < 4; ++reg) {
        int row = r0 + w*32 + m*16 + grp*4 + reg;
        if (CATM == 1) {
          int n = row >> 5, b = row & 31;
          const float* hp = inp + ((size_t)(b*LL + t)*NN + n)*2;
          z[(size_t)row*CE + 64] = hp[0];
          z[(size_t)row*CE + 65] = hp[1];
        } else {
          z[(size_t)row*CE + 64] = inp[row];
          z[(size_t)row*CE + 65] = 0.0f;
        }
      }
  }
}

// ---------------- cand GEMM (MFMA bf16x3): c = tanh(A@Wc+bc); h = u*h + (1-u)*c ----------------
template<bool DEC>
__global__ __launch_bounds__(256, 2) void k_gemm_cand(
    const float* __restrict__ z, const float* __restrict__ T1, const float* __restrict__ T2,
    const unsigned short* __restrict__ Bpack, const float* __restrict__ bc,
    const float* __restrict__ Ug, const float* __restrict__ hold,
    float* __restrict__ hnew, const float* __restrict__ Wp, const float* __restrict__ bp,
    float* __restrict__ out, float* __restrict__ xio, int t) {
  __shared__ unsigned short Bl[PACK_HALF];
  const int CIN_ = DEC ? 1 : 2;
  int r0 = blockIdx.x * 128;
  int tid = threadIdx.x;
  {
    const float4* src = (const float4*)Bpack;
    float4* dst = (float4*)Bl;
    #pragma unroll
    for (int i = 0; i < 14; ++i) dst[tid + 256*i] = src[tid + 256*i];
  }
  __syncthreads();
  int w = tid >> 6, lane = tid & 63, grp = lane >> 4, l15 = lane & 15;
  int row0 = r0 + w*32 + l15;
  int row1 = row0 + 16;
  ffrag acc[2][4];
  #pragma unroll
  for (int m = 0; m < 2; ++m)
    #pragma unroll
    for (int nf = 0; nf < 4; ++nf) acc[m][nf] = (ffrag){0.f, 0.f, 0.f, 0.f};

  #pragma unroll
  for (int ks = 0; ks < 6; ++ks) {
    int ko = (ks & 1)*32 + grp*8;
    const float* p0 = (ks < 2) ? z : ((ks < 4) ? T1 : T2);
    const float* a0p = p0 + (size_t)row0*CE + ko;
    const float* a1p = p0 + (size_t)row1*CE + ko;
    float av0[8], av1[8];
    *(float4*)(av0)   = *(const float4*)a0p; *(float4*)(av0+4) = *(const float4*)(a0p+4);
    *(float4*)(av1)   = *(const float4*)a1p; *(float4*)(av1+4) = *(const float4*)(a1p+4);
    bfrag ah0, al0, ah1, al1;
    cvt8(av0, &ah0, &al0); cvt8(av1, &ah1, &al1);
    #pragma unroll
    for (int nf = 0; nf < 4; ++nf) {
      bfrag bh  = *(const bfrag*)(Bl + ((((size_t)ks*4 + nf)*2 + 0)*64 + lane)*8);
      bfrag blo = *(const bfrag*)(Bl + ((((size_t)ks*4 + nf)*2 + 1)*64 + lane)*8);
      acc[0][nf] = __builtin_amdgcn_mfma_f32_16x16x32_bf16(ah0, bh,  acc[0][nf], 0, 0, 0);
      acc[0][nf] = __builtin_amdgcn_mfma_f32_16x16x32_bf16(ah0, blo, acc[0][nf], 0, 0, 0);
      acc[0][nf] = __builtin_amdgcn_mfma_f32_16x16x32_bf16(al0, bh,  acc[0][nf], 0, 0, 0);
      acc[1][nf] = __builtin_amdgcn_mfma_f32_16x16x32_bf16(ah1, bh,  acc[1][nf], 0, 0, 0);
      acc[1][nf] = __builtin_amdgcn_mfma_f32_16x16x32_bf16(ah1, blo, acc[1][nf], 0, 0, 0);
      acc[1][nf] = __builtin_amdgcn_mfma_f32_16x16x32_bf16(al1, bh,  acc[1][nf], 0, 0, 0);
    }
  }
  {
    float av0[8] = {0,0,0,0,0,0,0,0}, av1[8] = {0,0,0,0,0,0,0,0};
    if (grp == 0) {
      auto gx = [&](int row, float* av) {
        #pragma unroll
        for (int q = 0; q < CIN_; ++q) av[q] = z[(size_t)row*CE + 64 + q];
        #pragma unroll
        for (int q = 0; q < CIN_; ++q) av[CIN_ + q] = T1[(size_t)row*CE + 64 + q];
        #pragma unroll
        for (int q = 0; q < CIN_; ++q) av[2*CIN_ + q] = T2[(size_t)row*CE + 64 + q];
      };
      gx(row0, av0); gx(row1, av1);
    }
    bfrag ah0, al0, ah1, al1;
    cvt8(av0, &ah0, &al0); cvt8(av1, &ah1, &al1);
    #pragma unroll
    for (int nf = 0; nf < 4; ++nf) {
      bfrag bh  = *(const bfrag*)(Bl + ((((size_t)6*4 + nf)*2 + 0)*64 + lane)*8);
      bfrag blo = *(const bfrag*)(Bl + ((((size_t)6*4 + nf)*2 + 1)*64 + lane)*8);
      acc[0][nf] = __builtin_amdgcn_mfma_f32_16x16x32_bf16(ah0, bh,  acc[0][nf], 0, 0, 0);
      acc[0][nf] = __builtin_amdgcn_mfma_f32_16x16x32_bf16(ah0, blo, acc[0][nf], 0, 0, 0);
      acc[0][nf] = __builtin_amdgcn_mfma_f32_16x16x32_bf16(al0, bh,  acc[0][nf], 0, 0, 0);
      acc[1][nf] = __builtin_amdgcn_mfma_f32_16x16x32_bf16(ah1, bh,  acc[1][nf], 0, 0, 0);
      acc[1][nf] = __builtin_amdgcn_mfma_f32_16x16x32_bf16(ah1, blo, acc[1][nf], 0, 0, 0);
      acc[1][nf] = __builtin_amdgcn_mfma_f32_16x16x32_bf16(al1, bh,  acc[1][nf], 0, 0, 0);
    }
  }

  float bcv[4], wpv[4];
  #pragma unroll
  for (int nf = 0; nf < 4; ++nf) {
    bcv[nf] = bc[nf*16 + l15];
    wpv[nf] = DEC ? Wp[nf*16 + l15] : 0.f;
  }
  float bp0 = DEC ? bp[0] : 0.f;
  #pragma unroll
  for (int m = 0; m < 2; ++m)
    #pragma unroll
    for (int reg = 0; reg < 4; ++reg) {
      int row = r0 + w*32 + m*16 + grp*4 + reg;
      float p = 0.f;
      #pragma unroll
      for (int nf = 0; nf < 4; ++nf) {
        int col = nf*16 + l15;
        float cf = tanhf(acc[m][nf][reg] + bcv[nf]);
        float u  = Ug[(size_t)row*UU + col];
        float ho = hold[(size_t)row*UU + col];
        float hv = u * ho + (1.0f - u) * cf;
        hnew[(size_t)row*UU + col] = hv;
        if (DEC) p = fmaf(hv, wpv[nf], p);
      }
      if (DEC) {
        p += __shfl_xor(p, 1, 64);
        p += __shfl_xor(p, 2, 64);
        p += __shfl_xor(p, 4, 64);
        p += __shfl_xor(p, 8, 64);
        if (l15 == 0) {
          float val = p + bp0;
          int n = row >> 5, b = row & 31;
          out[((size_t)b*HHH + t)*NN + n] = val;
          xio[row] = val;
        }
      }
    }
}

extern "C" void kernel_launch(void* const* d_in, const int* in_sizes, int n_in,
                              void* d_out, int out_size, void* d_ws, size_t ws_size,
                              hipStream_t stream) {
  (void)in_sizes; (void)n_in; (void)out_size; (void)ws_size;
  const float* hist = (const float*)d_in[0];
  const float* support = (const float*)d_in[1];
  const float* eWg = (const float*)d_in[2];
  const float* ebg = (const float*)d_in[3];
  const float* eWc = (const float*)d_in[4];
  const float* ebc = (const float*)d_in[5];
  const float* dWg = (const float*)d_in[6];
  const float* dbg = (const float*)d_in[7];
  const float* dWc = (const float*)d_in[8];
  const float* dbc = (const float*)d_in[9];
  const float* Wp  = (const float*)d_in[10];
  const float* bp  = (const float*)d_in[11];
  float* out = (float*)d_out;

  char* base = (char*)d_ws;
  size_t off = 0;
  auto carve = [&](size_t bytes) -> void* {
    void* p = base + off;
    off += (bytes + 255) & ~(size_t)255;
    return p;
  };
  int*   cnt   = (int*)carve(NN * 4);
  int*   rpB   = (int*)carve((NN + 1) * 4);
  int*   colsB = (int*)carve(CSR_CAP * 4);
  float* valsB = (float*)carve(CSR_CAP * 4);
  unsigned short* Pge = (unsigned short*)carve(2 * PACK_HALF * 2);
  unsigned short* Pgd = (unsigned short*)carve(2 * PACK_HALF * 2);
  unsigned short* Pce = (unsigned short*)carve((size_t)PACK_HALF * 2);
  unsigned short* Pcd = (unsigned short*)carve((size_t)PACK_HALF * 2);
  float* T1    = (float*)carve((size_t)NN * WID * 4);
  float* T2    = (float*)carve((size_t)NN * WID * 4);
  float* zB    = (float*)carve((size_t)MR * CE * 4);
  float* Ug    = (float*)carve((size_t)MR * UU * 4);
  float* ha    = (float*)carve((size_t)MR * UU * 4);
  float* hb    = (float*)carve((size_t)MR * UU * 4);
  float* xio   = (float*)carve((size_t)MR * 4);

  hipMemsetAsync(ha, 0, (size_t)MR * UU * 4, stream);
  hipMemsetAsync(xio, 0, (size_t)MR * 4, stream);

  k_row_count<<<NN, 256, 0, stream>>>(support, cnt);
  k_scan<<<1, 256, 0, stream>>>(cnt, rpB);
  k_fill<<<NN, 256, 0, stream>>>(support, rpB, colsB, valsB);
  k_pack<<<112, 256, 0, stream>>>(eWg, Pge, 2, 128);
  k_pack<<<56, 256, 0, stream>>>(eWc, Pce, 2, 64);
  k_pack<<<112, 256, 0, stream>>>(dWg, Pgd, 1, 128);
  k_pack<<<56, 256, 0, stream>>>(dWc, Pcd, 1, 64);

  float* hc = ha; float* hn = hb;
  for (int t = 0; t < LL; ++t) {
    k_spmm<1, -1><<<8192, 256, 0, stream>>>(rpB, colsB, valsB, nullptr, hist, hc,
                                            nullptr, nullptr, nullptr, T1, t);
    k_spmm<0, 1><<<8192, 256, 0, stream>>>(rpB, colsB, valsB, T1, nullptr, nullptr,
                                           nullptr, hist, hc, T2, t);
    k_gemm_gate<1><<<MR / 64, 256, 0, stream>>>(hist, hc, T1, T2, Pge, ebg, zB, Ug, t);
    k_spmm<0, -1><<<8192, 256, 0, stream>>>(rpB, colsB, valsB, zB, nullptr, nullptr,
                                            nullptr, nullptr, nullptr, T1, t);
    k_spmm<0, 0><<<8192, 256, 0, stream>>>(rpB, colsB, valsB, T1, nullptr, nullptr,
                                           zB, nullptr, nullptr, T2, t);
    k_gemm_cand<false><<<MR / 128, 256, 0, stream>>>(zB, T1, T2, Pce, ebc, Ug, hc, hn,
                                                     Wp, bp, out, xio, t);
    float* tmp = hc; hc = hn; hn = tmp;
  }
  for (int t = 0; t < HHH; ++t) {
    k_spmm<2, -1><<<8192, 256, 0, stream>>>(rpB, colsB, valsB, nullptr, xio, hc,
                                            nullptr, nullptr, nullptr, T1, t);
    k_spmm<0, 2><<<8192, 256, 0, stream>>>(rpB, colsB, valsB, T1, nullptr, nullptr,
                                           nullptr, xio, hc, T2, t);
    k_gemm_gate<2><<<MR / 64, 256, 0, stream>>>(xio, hc, T1, T2, Pgd, dbg, zB, Ug, t);
    k_spmm<0, -1><<<8192, 256, 0, stream>>>(rpB, colsB, valsB, zB, nullptr, nullptr,
                                            nullptr, nullptr, nullptr, T1, t);
    k_spmm<0, 0><<<8192, 256, 0, stream>>>(rpB, colsB, valsB, T1, nullptr, nullptr,
                                           zB, nullptr, nullptr, T2, t);
    k_gemm_cand<true><<<MR / 128, 256, 0, stream>>>(zB, T1, T2, Pcd, dbc, Ug, hc, hn,
                                                    Wp, bp, out, xio, t);
    float* tmp = hc; hc = hn; hn = tmp;
  }
}